// Round 8
// baseline (322.032 us; speedup 1.0000x reference)
//
#include <hip/hip_runtime.h>
#include <math.h>

#define Bn 32
#define Ln 512
#define Hn 256
#define NHn 4
#define DHn 64

typedef __attribute__((ext_vector_type(8))) short bf16x8;
typedef __attribute__((ext_vector_type(4))) float f32x4;
typedef unsigned int uint32;

__device__ __forceinline__ short f2b(float f) {
    union { float f; uint32 u; } v; v.f = f;
    uint32 r = (v.u + 0x7FFFu + ((v.u >> 16) & 1u)) >> 16;
    return (short)r;
}
__device__ __forceinline__ float b2f(short h) {
    union { uint32 u; float f; } v; v.u = ((uint32)(unsigned short)h) << 16;
    return v.f;
}
__device__ __forceinline__ bf16x8 cvt8(float4 a, float4 b) {
    bf16x8 o;
    o[0] = f2b(a.x); o[1] = f2b(a.y); o[2] = f2b(a.z); o[3] = f2b(a.w);
    o[4] = f2b(b.x); o[5] = f2b(b.y); o[6] = f2b(b.z); o[7] = f2b(b.w);
    return o;
}
// fast tanh: 1 - 2/(e^{2x}+1); exact limits at +-inf
__device__ __forceinline__ float fast_tanh(float x) {
    float e = __expf(2.f * x);
    return 1.f - 2.f * __builtin_amdgcn_rcpf(e + 1.f);
}
__device__ __forceinline__ float fast_sigmoid(float x) {
    return __builtin_amdgcn_rcpf(1.f + __expf(-x));
}

// ---------------- QKV/TQ projection: per-tensor blocks, BK=128, reg-prefetch ----------------
// grid (16, 256): bx = tensor*4 + ncol-block, by = m-block. Inline fp32->bf16
// conversion of x and W (replaces conv_kernel; identical RNE rounding).
// Blocks with by==0 additionally convert Wd -> wdb for outln.
__global__ __launch_bounds__(256) void proj_kernel(
    const float* __restrict__ x,
    const float* __restrict__ Wq, const float* __restrict__ Wk,
    const float* __restrict__ Wv, const float* __restrict__ Wtq,
    const float* __restrict__ Wd,
    const float* __restrict__ bq, const float* __restrict__ bk,
    const float* __restrict__ bv, const float* __restrict__ btq,
    short* __restrict__ qb, short* __restrict__ kb,
    short* __restrict__ vb, short* __restrict__ tqb,
    short* __restrict__ wdb)
{
    __shared__ short As[64 * 136];
    __shared__ short Bs[64 * 136];
    const int tid = threadIdx.x;

    // side job: convert Wd (16 blocks x 4096 elts)
    if (blockIdx.y == 0) {
        int base = blockIdx.x * 4096 + tid * 16;
#pragma unroll
        for (int j = 0; j < 4; ++j) {
            float4 v = *(const float4*)(Wd + base + j * 4);
            short4 o; o.x = f2b(v.x); o.y = f2b(v.y); o.z = f2b(v.z); o.w = f2b(v.w);
            *(short4*)(wdb + base + j * 4) = o;
        }
    }

    const int tensor = blockIdx.x >> 2;
    const int ncol0 = (blockIdx.x & 3) * 64;
    const int m0 = blockIdx.y * 64;
    const float* Wsrc = (tensor == 0) ? Wq : (tensor == 1) ? Wk : (tensor == 2) ? Wv : Wtq;
    const float* bias = (tensor == 0) ? bq : (tensor == 1) ? bk : (tensor == 2) ? bv : btq;
    short* out = (tensor == 0) ? qb : (tensor == 1) ? kb : (tensor == 2) ? vb : tqb;

    const int lane = tid & 63, w = tid >> 6;
    const int quad = lane >> 4, lm = lane & 15;
    const int srow = tid >> 2;          // 0..63
    const int cb = (tid & 3) * 32;      // col chunk base

    f32x4 acc[4];
#pragma unroll
    for (int i = 0; i < 4; ++i) acc[i] = (f32x4){0.f, 0.f, 0.f, 0.f};

    // prefetch tile 0 (fp32)
    float4 fa[8], fb[8];
#pragma unroll
    for (int j = 0; j < 4; ++j) {
        fa[2*j]   = *(const float4*)(x + (size_t)(m0 + srow) * Hn + cb + j * 8);
        fa[2*j+1] = *(const float4*)(x + (size_t)(m0 + srow) * Hn + cb + j * 8 + 4);
        fb[2*j]   = *(const float4*)(Wsrc + (size_t)(ncol0 + srow) * Hn + cb + j * 8);
        fb[2*j+1] = *(const float4*)(Wsrc + (size_t)(ncol0 + srow) * Hn + cb + j * 8 + 4);
    }

    for (int it = 0; it < 2; ++it) {
        __syncthreads();
#pragma unroll
        for (int j = 0; j < 4; ++j) {
            *(bf16x8*)(As + srow * 136 + cb + j * 8) = cvt8(fa[2*j], fa[2*j+1]);
            *(bf16x8*)(Bs + srow * 136 + cb + j * 8) = cvt8(fb[2*j], fb[2*j+1]);
        }
        __syncthreads();
        if (it == 0) {
#pragma unroll
            for (int j = 0; j < 4; ++j) {
                fa[2*j]   = *(const float4*)(x + (size_t)(m0 + srow) * Hn + 128 + cb + j * 8);
                fa[2*j+1] = *(const float4*)(x + (size_t)(m0 + srow) * Hn + 128 + cb + j * 8 + 4);
                fb[2*j]   = *(const float4*)(Wsrc + (size_t)(ncol0 + srow) * Hn + 128 + cb + j * 8);
                fb[2*j+1] = *(const float4*)(Wsrc + (size_t)(ncol0 + srow) * Hn + 128 + cb + j * 8 + 4);
            }
        }
#pragma unroll
        for (int ks = 0; ks < 4; ++ks) {
            bf16x8 a = *(const bf16x8*)(As + (w * 16 + lm) * 136 + ks * 32 + quad * 8);
#pragma unroll
            for (int kt = 0; kt < 4; ++kt) {
                bf16x8 b = *(const bf16x8*)(Bs + (kt * 16 + lm) * 136 + ks * 32 + quad * 8);
                acc[kt] = __builtin_amdgcn_mfma_f32_16x16x32_bf16(a, b, acc[kt], 0, 0, 0);
            }
        }
    }

#pragma unroll
    for (int kt = 0; kt < 4; ++kt) {
        int n = ncol0 + kt * 16 + lm;
        float bs = bias[n];
#pragma unroll
        for (int r = 0; r < 4; ++r) {
            int row = m0 + w * 16 + quad * 4 + r;
            out[(size_t)row * Hn + n] = f2b(acc[kt][r] + bs);
        }
    }
}

// ---------------- time-decay gate: BK=128 + reg-prefetch; packs {gate,mask} u32 ----------------
__global__ __launch_bounds__(256) void gate_kernel(
    const short* __restrict__ tqb, const float* __restrict__ x,
    const float* __restrict__ tseq, const float* __restrict__ mask,
    const float* __restrict__ tw1, const float* __restrict__ tb1,
    const float* __restrict__ tow1, const float* __restrict__ tow2,
    const float* __restrict__ tob,
    uint32* __restrict__ gm)
{
    __shared__ short As[64 * 136];
    __shared__ short Bs[64 * 136];
    const int b = blockIdx.z;
    const int m0 = blockIdx.y * 64, n0 = blockIdx.x * 64;
    const int tid = threadIdx.x;
    const int lane = tid & 63, w = tid >> 6;
    const int quad = lane >> 4, lm = lane & 15;
    const int srow = tid >> 2, cb = (tid & 3) * 32;

    const short* Abase = tqb + ((size_t)b * Ln + m0) * Hn;
    const float* Bbase = x + ((size_t)b * Ln + n0) * Hn;

    f32x4 acc[4];
#pragma unroll
    for (int i = 0; i < 4; ++i) acc[i] = (f32x4){0.f, 0.f, 0.f, 0.f};

    bf16x8 ka[4]; float4 fb[8];
#pragma unroll
    for (int j = 0; j < 4; ++j) {
        ka[j]     = *(const bf16x8*)(Abase + (size_t)srow * Hn + cb + j * 8);
        fb[2*j]   = *(const float4*)(Bbase + (size_t)srow * Hn + cb + j * 8);
        fb[2*j+1] = *(const float4*)(Bbase + (size_t)srow * Hn + cb + j * 8 + 4);
    }

    for (int it = 0; it < 2; ++it) {
        __syncthreads();
#pragma unroll
        for (int j = 0; j < 4; ++j) {
            *(bf16x8*)(As + srow * 136 + cb + j * 8) = ka[j];
            *(bf16x8*)(Bs + srow * 136 + cb + j * 8) = cvt8(fb[2*j], fb[2*j+1]);
        }
        __syncthreads();
        if (it == 0) {
#pragma unroll
            for (int j = 0; j < 4; ++j) {
                ka[j]     = *(const bf16x8*)(Abase + (size_t)srow * Hn + 128 + cb + j * 8);
                fb[2*j]   = *(const float4*)(Bbase + (size_t)srow * Hn + 128 + cb + j * 8);
                fb[2*j+1] = *(const float4*)(Bbase + (size_t)srow * Hn + 128 + cb + j * 8 + 4);
            }
        }
#pragma unroll
        for (int ks = 0; ks < 4; ++ks) {
            bf16x8 a = *(const bf16x8*)(As + (w * 16 + lm) * 136 + ks * 32 + quad * 8);
#pragma unroll
            for (int kt = 0; kt < 4; ++kt) {
                bf16x8 bfr = *(const bf16x8*)(Bs + (kt * 16 + lm) * 136 + ks * 32 + quad * 8);
                acc[kt] = __builtin_amdgcn_mfma_f32_16x16x32_bf16(a, bfr, acc[kt], 0, 0, 0);
            }
        }
    }

    const float* ts = tseq + (size_t)b * Ln;
    const float* mk = mask + (size_t)b * Ln * Ln;
    uint32* gout = gm + (size_t)b * Ln * Ln;
    float ti[4];
#pragma unroll
    for (int r = 0; r < 4; ++r) ti[r] = ts[m0 + w * 16 + quad * 4 + r];
#pragma unroll
    for (int kt = 0; kt < 4; ++kt) {
        int j = n0 + kt * 16 + lm;
        float tj = ts[j];
#pragma unroll
        for (int r = 0; r < 4; ++r) {
            int i = m0 + w * 16 + quad * 4 + r;
            size_t ij = (size_t)i * Ln + j;
            float lg = __logf(1.f + fabsf(ti[r] - tj));
            float dec = fast_tanh(lg * tw1[ij] + tb1[ij]);
            float tqk = fast_tanh(acc[kt][r]);
            float dg = tow1[ij] * dec + tow2[ij] * tqk + tob[ij];
            float g = 0.125f * fast_sigmoid(dg);
            uint32 pk = (uint32)(unsigned short)f2b(g) |
                        ((uint32)(unsigned short)f2b(mk[ij]) << 16);
            gout[ij] = pk;
        }
    }
}

// ---------------- flash attention: BK=128, register-prefetch pipeline (r7, unchanged) ----------------
__global__ __launch_bounds__(256) void flash_mfma(
    const short* __restrict__ qb, const short* __restrict__ kb,
    const short* __restrict__ vb, const uint32* __restrict__ gm,
    short* __restrict__ ctxb)
{
    __shared__ short Ks[128 * 72];
    __shared__ short Vt[64 * 136];
    __shared__ short Ps[4 * 16 * 136];
    const int q0 = blockIdx.x * 64;
    const int h = blockIdx.y, b = blockIdx.z;
    const int tid = threadIdx.x;
    const int w = tid >> 6, lane = tid & 63;
    const int quad = lane >> 4, lm = lane & 15;

    bf16x8 qf0, qf1;
    {
        const short* qrow = qb + ((size_t)(b * Ln + q0 + w * 16 + lm)) * Hn + h * DHn;
        qf0 = *(const bf16x8*)(qrow + quad * 8);
        qf1 = *(const bf16x8*)(qrow + 32 + quad * 8);
    }

    f32x4 o[4];
#pragma unroll
    for (int i = 0; i < 4; ++i) o[i] = (f32x4){0.f, 0.f, 0.f, 0.f};
    float lpart[4] = {0.f, 0.f, 0.f, 0.f};

    const uint32* gmb = gm + (size_t)b * Ln * Ln;
    const int qrow0 = q0 + w * 16 + quad * 4;

    const int srow = tid >> 3, slot = tid & 7;
    const int kp = tid & 63;
    const short* kbase = kb + ((size_t)b * Ln) * Hn + h * DHn;
    const short* vbase = vb + ((size_t)b * Ln) * Hn + h * DHn;

    bf16x8 kr[4], va0, va1, vc0, vc1;
#pragma unroll
    for (int i = 0; i < 4; ++i)
        kr[i] = *(const bf16x8*)(kbase + (size_t)(srow + 32 * i) * Hn + slot * 8);
    va0 = *(const bf16x8*)(vbase + (size_t)(2 * kp) * Hn + w * 16);
    va1 = *(const bf16x8*)(vbase + (size_t)(2 * kp) * Hn + w * 16 + 8);
    vc0 = *(const bf16x8*)(vbase + (size_t)(2 * kp + 1) * Hn + w * 16);
    vc1 = *(const bf16x8*)(vbase + (size_t)(2 * kp + 1) * Hn + w * 16 + 8);

    for (int k0 = 0; k0 < Ln; k0 += 128) {
        __syncthreads();
#pragma unroll
        for (int i = 0; i < 4; ++i)
            *(bf16x8*)(Ks + (srow + 32 * i) * 72 + slot * 8) = kr[i];
#pragma unroll
        for (int u = 0; u < 8; ++u) {
            uint32 p0 = (uint32)(unsigned short)va0[u] | ((uint32)(unsigned short)vc0[u] << 16);
            uint32 p1 = (uint32)(unsigned short)va1[u] | ((uint32)(unsigned short)vc1[u] << 16);
            *(uint32*)&Vt[(w * 16 + u) * 136 + 2 * kp] = p0;
            *(uint32*)&Vt[(w * 16 + 8 + u) * 136 + 2 * kp] = p1;
        }
        __syncthreads();

        if (k0 + 128 < Ln) {
            const short* kn = kbase + (size_t)(k0 + 128) * Hn;
            const short* vn = vbase + (size_t)(k0 + 128) * Hn;
#pragma unroll
            for (int i = 0; i < 4; ++i)
                kr[i] = *(const bf16x8*)(kn + (size_t)(srow + 32 * i) * Hn + slot * 8);
            va0 = *(const bf16x8*)(vn + (size_t)(2 * kp) * Hn + w * 16);
            va1 = *(const bf16x8*)(vn + (size_t)(2 * kp) * Hn + w * 16 + 8);
            vc0 = *(const bf16x8*)(vn + (size_t)(2 * kp + 1) * Hn + w * 16);
            vc1 = *(const bf16x8*)(vn + (size_t)(2 * kp + 1) * Hn + w * 16 + 8);
        }

        uint32 gmr[8][4];
#pragma unroll
        for (int kt = 0; kt < 8; ++kt) {
            int col = k0 + kt * 16 + lm;
#pragma unroll
            for (int r = 0; r < 4; ++r)
                gmr[kt][r] = gmb[(size_t)(qrow0 + r) * Ln + col];
        }

        f32x4 s[8];
#pragma unroll
        for (int kt = 0; kt < 8; ++kt) {
            s[kt] = (f32x4){0.f, 0.f, 0.f, 0.f};
            bf16x8 b0 = *(const bf16x8*)(Ks + (kt * 16 + lm) * 72 + quad * 8);
            s[kt] = __builtin_amdgcn_mfma_f32_16x16x32_bf16(qf0, b0, s[kt], 0, 0, 0);
            bf16x8 b1 = *(const bf16x8*)(Ks + (kt * 16 + lm) * 72 + 32 + quad * 8);
            s[kt] = __builtin_amdgcn_mfma_f32_16x16x32_bf16(qf1, b1, s[kt], 0, 0, 0);
        }

        short* pw = Ps + w * 16 * 136;
#pragma unroll
        for (int kt = 0; kt < 8; ++kt) {
#pragma unroll
            for (int r = 0; r < 4; ++r) {
                uint32 pk2 = gmr[kt][r];
                float g = b2f((short)(pk2 & 0xFFFFu));
                float m = b2f((short)(pk2 >> 16));
                float pv = __expf(s[kt][r] * g + m);
                lpart[r] += pv;
                pw[(quad * 4 + r) * 136 + kt * 16 + lm] = f2b(pv);
            }
        }
#pragma unroll
        for (int ks = 0; ks < 4; ++ks) {
            bf16x8 pa = *(const bf16x8*)(pw + lm * 136 + ks * 32 + quad * 8);
#pragma unroll
            for (int ot = 0; ot < 4; ++ot) {
                bf16x8 vv = *(const bf16x8*)(Vt + (ot * 16 + lm) * 136 + ks * 32 + quad * 8);
                o[ot] = __builtin_amdgcn_mfma_f32_16x16x32_bf16(pa, vv, o[ot], 0, 0, 0);
            }
        }
    }

#pragma unroll
    for (int r = 0; r < 4; ++r) {
        float lv = lpart[r];
#pragma unroll
        for (int off = 1; off < 16; off <<= 1) lv += __shfl_xor(lv, off, 64);
        float inv = 1.0f / lv;
        int row = b * Ln + qrow0 + r;
#pragma unroll
        for (int ot = 0; ot < 4; ++ot) {
            int d = h * DHn + ot * 16 + lm;
            ctxb[(size_t)row * Hn + d] = f2b(o[ot][r] * inv);
        }
    }
}

// ---------------- fused output projection + residual + LayerNorm + prediction ----------------
// Each block owns 64 rows x all 256 cols of one batch -> the block holding row
// len-1 (len-2) computes the full prediction dot and atomicAdds into pred[b]
// (pred zeroed via hipMemsetAsync; len-1 block adds bt).
__global__ __launch_bounds__(256) void outln_kernel(
    const short* __restrict__ ctxb, const short* __restrict__ wdb,
    const float* __restrict__ bd, const float* __restrict__ x,
    const float* __restrict__ lng, const float* __restrict__ lnb,
    const int* __restrict__ lens, const float* __restrict__ Wt,
    const float* __restrict__ bt,
    float* __restrict__ out, float* __restrict__ pred)
{
    const int m0 = blockIdx.x * 64;
    const int tid = threadIdx.x;
    const int w = tid >> 6, lane = tid & 63;
    const int quad = lane >> 4, lm = lane & 15;

    f32x4 acc[16];
#pragma unroll
    for (int i = 0; i < 16; ++i) acc[i] = (f32x4){0.f, 0.f, 0.f, 0.f};

    const short* arow = ctxb + (size_t)(m0 + w * 16 + lm) * Hn;
#pragma unroll
    for (int ks = 0; ks < 8; ++ks) {
        bf16x8 af = *(const bf16x8*)(arow + ks * 32 + quad * 8);
#pragma unroll
        for (int nt = 0; nt < 16; ++nt) {
            bf16x8 bf_ = *(const bf16x8*)(wdb + (size_t)(nt * 16 + lm) * Hn + ks * 32 + quad * 8);
            acc[nt] = __builtin_amdgcn_mfma_f32_16x16x32_bf16(af, bf_, acc[nt], 0, 0, 0);
        }
    }

    float s1[4] = {0.f, 0.f, 0.f, 0.f}, s2[4] = {0.f, 0.f, 0.f, 0.f};
#pragma unroll
    for (int nt = 0; nt < 16; ++nt) {
        int col = nt * 16 + lm;
        float bv = bd[col];
#pragma unroll
        for (int r = 0; r < 4; ++r) {
            int row = m0 + w * 16 + quad * 4 + r;
            float v = acc[nt][r] + bv + x[(size_t)row * Hn + col];
            acc[nt][r] = v;
            s1[r] += v; s2[r] += v * v;
        }
    }
    float muv[4], rstd[4];
#pragma unroll
    for (int r = 0; r < 4; ++r) {
        float a = s1[r], b2 = s2[r];
#pragma unroll
        for (int off = 1; off < 16; off <<= 1) {
            a += __shfl_xor(a, off, 64);
            b2 += __shfl_xor(b2, off, 64);
        }
        float mu = a * (1.f / 256.f);
        float var = b2 * (1.f / 256.f) - mu * mu;
        muv[r] = mu;
        rstd[r] = rsqrtf(var + 1e-12f);
    }

    // prediction row targets
    const int b0 = m0 >> 9;                 // batch (512 rows/batch, 64 | 512)
    const int m0loc = m0 & 511;
    const int len = lens[b0];
    const int l1 = len - 1 - m0loc, l2 = len - 2 - m0loc;
    const bool in1 = (l1 >= 0 && l1 < 64) && (w == (l1 >> 4));
    const bool in2 = (l2 >= 0 && l2 < 64) && (w == (l2 >> 4));
    const int q1 = (l1 >> 2) & 3, r1 = l1 & 3;
    const int q2 = (l2 >> 2) & 3, r2 = l2 & 3;
    float pp1 = 0.f, pp2 = 0.f;

#pragma unroll
    for (int nt = 0; nt < 16; ++nt) {
        int col = nt * 16 + lm;
        float gg = lng[col], bb = lnb[col];
        float ov[4];
#pragma unroll
        for (int r = 0; r < 4; ++r) {
            int row = m0 + w * 16 + quad * 4 + r;
            float v = (acc[nt][r] - muv[r]) * rstd[r] * gg + bb;
            ov[r] = v;
            out[(size_t)row * Hn + col] = v;
        }
        if (in1 && quad == q1) {
            float v = (r1 == 0) ? ov[0] : (r1 == 1) ? ov[1] : (r1 == 2) ? ov[2] : ov[3];
            pp1 += v * Wt[col];
        }
        if (in2 && quad == q2) {
            float v = (r2 == 0) ? ov[0] : (r2 == 1) ? ov[1] : (r2 == 2) ? ov[2] : ov[3];
            pp2 += v * Wt[Hn + col];
        }
    }
#pragma unroll
    for (int off = 1; off < 16; off <<= 1) {
        pp1 += __shfl_xor(pp1, off, 64);
        pp2 += __shfl_xor(pp2, off, 64);
    }
    if (in1 && quad == q1 && lm == 0) atomicAdd(&pred[b0], pp1 + bt[0]);
    if (in2 && quad == q2 && lm == 0) atomicAdd(&pred[b0], pp2);
}

extern "C" void kernel_launch(void* const* d_in, const int* in_sizes, int n_in,
                              void* d_out, int out_size, void* d_ws, size_t ws_size,
                              hipStream_t stream) {
    (void)in_sizes; (void)n_in; (void)out_size; (void)ws_size;
    const float* x    = (const float*)d_in[0];
    const float* tseq = (const float*)d_in[1];
    const float* mask = (const float*)d_in[2];
    const int*   lens = (const int*)d_in[3];
    const float* Wq = (const float*)d_in[4];  const float* bq = (const float*)d_in[5];
    const float* Wk = (const float*)d_in[6];  const float* bk = (const float*)d_in[7];
    const float* Wv = (const float*)d_in[8];  const float* bv = (const float*)d_in[9];
    const float* Wd = (const float*)d_in[10]; const float* bd = (const float*)d_in[11];
    const float* ln_g = (const float*)d_in[12]; const float* ln_b = (const float*)d_in[13];
    const float* Wtq = (const float*)d_in[14]; const float* btq = (const float*)d_in[15];
    const float* tw1 = (const float*)d_in[16]; const float* tb1 = (const float*)d_in[17];
    const float* tow1 = (const float*)d_in[18]; const float* tow2 = (const float*)d_in[19];
    const float* tob = (const float*)d_in[20];
    const float* Wt = (const float*)d_in[21]; const float* bt = (const float*)d_in[22];

    const size_t NLH = (size_t)Bn * Ln * Hn;   // 4194304
    const size_t NLL = (size_t)Bn * Ln * Ln;   // 8388608
    short* ws = (short*)d_ws;
    short* qb    = ws;
    short* kb    = qb + NLH;
    short* vb    = kb + NLH;
    short* tqb   = vb + NLH;
    uint32* gm   = (uint32*)(tqb + NLH);       // B*L*L u32
    short* ctxb  = (short*)(gm + NLL);
    short* wdb   = ctxb + NLH;
    float* out   = (float*)d_out;
    float* pred  = out + NLH;

    dim3 blk(256);
    hipMemsetAsync(pred, 0, Bn * sizeof(float), stream);
    proj_kernel<<<dim3(16, 256), blk, 0, stream>>>(x, Wq, Wk, Wv, Wtq, Wd,
                                                   bq, bk, bv, btq, qb, kb, vb, tqb, wdb);
    gate_kernel<<<dim3(8, 8, Bn), blk, 0, stream>>>(tqb, x, tseq, mask, tw1, tb1, tow1, tow2, tob, gm);
    flash_mfma<<<dim3(8, NHn, Bn), blk, 0, stream>>>(qb, kb, vb, gm, ctxb);
    outln_kernel<<<dim3(256), blk, 0, stream>>>(ctxb, wdb, bd, x, ln_g, ln_b, lens, Wt, bt, out, pred);
}